// Round 8
// baseline (226.259 us; speedup 1.0000x reference)
//
#include <hip/hip_runtime.h>
#include <hip/hip_bf16.h>

// ContrastiveLoss: loss = mean_i [ logsumexp_j(logits[i,:]) - pos_sim[i,i] ]
// logits = [20*xn@tn^T | 20*xn@hn^T + I], rows normalized.
// Round 16: NO-LDS gemm. R15 pipe audit (45.6us = 109k cyc/CU): LDS pipe
// 61k cyc (56%, read 49k + staging-write 12k) is the largest single pipe;
// MFMA 42k; L2 15.5k. acc 4x4 is the reuse ceiling at this occupancy, so
// the LDS pipe can't shrink -- remove it. With the R14/R15-proven 2D XCD
// partition the tile working set is L2-resident (FETCH 16.5MB), and a
// 16B/lane frag load from global touches the SAME 16x64B lines as the
// staged path (m169: stage only when data doesn't cache-fit). Frag traffic
// 4.1MB/CU from L2 @135B/cyc = ~13us < MFMA floor 17.4us.
//  - No barriers at all (R9-R12's serializer gone); waves independent.
//  - 2-deep register ping-pong (P/Q = 8 frags each, 32V): issue step s+1's
//    8 global_load_dwordx4, MFMA step s. All offsets compile-time imms
//    (full unroll, koff<=960 fits the 13-bit signed offset field).
//  - ~154 regs (64 acc + ~90 arch) -> launch_bounds(256,3), 12 waves/CU.
//  - Epilogue/normalize/finalize = R15 verbatim (absmax 0.0 proven).
//  - scaled-MFMA banned (R2/R4); device fences in hot path banned (R14).
//  - logit = acc * (20/127^2); diag cancellation keeps i8 loss error ~1e-3.

#define AS1 __attribute__((address_space(1)))
#define AS3 __attribute__((address_space(3)))

constexpr int N = 4096;
constexpr int D = 1024;            // elements per row == bytes per i8 row
constexpr float QSCALE = 127.0f;
constexpr float LSCALE = 20.0f / (127.0f * 127.0f);  // acc -> logit
constexpr float CBIAS = 21.0f;     // >= max possible logit (20*1 + 1)

typedef int i32x4 __attribute__((ext_vector_type(4)));

// 3072 blocks x 256. One row per wave, 4 coalesced passes: pass j, lane L
// loads float4 #(L+64j) (1KB/inst contiguous) and stores the 4 quantized
// bytes as u32 #(L+64j) (256B/inst contiguous).
// Blocks 0..15 zero rowsum; block 0 zeroes out[0] for finalize's atomics.
__global__ __launch_bounds__(256) void normalize_kernel(
    const float* __restrict__ in0, const float* __restrict__ in1,
    const float* __restrict__ in2, unsigned char* __restrict__ Abuf,
    unsigned char* __restrict__ Bbuf, float* __restrict__ rowsum,
    float* __restrict__ outp) {
    const int t = threadIdx.x, lane = t & 63, wave = t >> 6;
    if (blockIdx.x < 16) rowsum[blockIdx.x * 256 + t] = 0.f;
    if (blockIdx.x == 0 && t == 0) outp[0] = 0.f;
    const int row = blockIdx.x * 4 + wave;  // 0..12287
    const int mat = row >> 12, r = row & (N - 1);
    const float* src = (mat == 0) ? in0 : (mat == 1) ? in1 : in2;
    unsigned char* dst = (mat == 0) ? (Abuf + (size_t)r * D)
                       : (mat == 1) ? (Bbuf + (size_t)r * D)
                                    : (Bbuf + (size_t)(r + N) * D);
    const float4* s4 = (const float4*)(src + (size_t)r * D);
    float4 v[4];
    float p = 0.f;
#pragma unroll
    for (int j = 0; j < 4; ++j) {
        v[j] = s4[lane + 64 * j];  // coalesced: 64 consecutive float4/inst
        p += v[j].x * v[j].x + v[j].y * v[j].y + v[j].z * v[j].z + v[j].w * v[j].w;
    }
#pragma unroll
    for (int m = 1; m < 64; m <<= 1) p += __shfl_xor(p, m);
    const float s = QSCALE / fmaxf(sqrtf(p), 1e-8f);
    unsigned int* d32 = (unsigned int*)dst;
#pragma unroll
    for (int j = 0; j < 4; ++j) {
        int q0 = min(127, max(-127, __float2int_rn(v[j].x * s)));
        int q1 = min(127, max(-127, __float2int_rn(v[j].y * s)));
        int q2 = min(127, max(-127, __float2int_rn(v[j].z * s)));
        int q3 = min(127, max(-127, __float2int_rn(v[j].w * s)));
        d32[lane + 64 * j] = (q0 & 255) | ((q1 & 255) << 8) | ((q2 & 255) << 16)
                           | ((unsigned)(q3 & 255) << 24);
    }
}

// 128x128 tile, 4 waves 2x2, wave 64x64 via 4x4 of 16x16x64 i8 MFMA.
// NO LDS: frags loaded straight from global (L2-resident under the 2D XCD
// partition). A:[N,D] i8, B:[2N,D] i8, row-major. Frag: row = lane&15,
// k-bytes (lane>>4)*16 within the 64B K-step at byte col s*64 (s=0..15).
// C/D: col = lane&15, row = (lane>>4)*4 + reg (m89-verified).
__global__ __launch_bounds__(256, 3) void gemm_lse_kernel(
    const unsigned char* __restrict__ A, const unsigned char* __restrict__ B,
    float* __restrict__ rowsum, float* __restrict__ posdiag) {
    const int tid = threadIdx.x;
    const int lane = tid & 63;
    const int wave = tid >> 6;
    const int wr = wave >> 1, wc = wave & 1;
    const int quad = lane >> 4, colid = lane & 15;

    // 2D XCD partition (R14/R15-proven: FETCH 39->16.5MB): XCD x owns the
    // 16x16-tile region rows [16*(x>>2),+16) x cols [16*(x&3),+16).
    const int flat = blockIdx.y * 64 + blockIdx.x;
    const int xcd = flat & 7, tt = flat >> 3;  // tt = 0..255 within XCD
    const int rowBase = (((xcd >> 2) << 4) + (tt & 15)) * 128;
    const int colBase = (((xcd & 3) << 4) + (tt >> 4)) * 128;

    i32x4 acc[4][4];
#pragma unroll
    for (int i = 0; i < 4; ++i)
#pragma unroll
        for (int j = 0; j < 4; ++j) acc[i][j] = {0, 0, 0, 0};

    // Per-lane frag base pointers (element = 16B): row rt*16+colid chunk
    // quad. K-step s (=0..15) is pa[rt][s*4] -> offset imm s*64 <= 960.
    const size_t rb = (size_t)(rowBase + wr * 64 + colid) * D + quad * 16;
    const size_t cb = (size_t)(colBase + wc * 64 + colid) * D + quad * 16;
    const i32x4* pa0 = (const i32x4*)(A + rb);
    const i32x4* pa1 = (const i32x4*)(A + rb + 16 * D);
    const i32x4* pa2 = (const i32x4*)(A + rb + 32 * D);
    const i32x4* pa3 = (const i32x4*)(A + rb + 48 * D);
    const i32x4* pb0 = (const i32x4*)(B + cb);
    const i32x4* pb1 = (const i32x4*)(B + cb + 16 * D);
    const i32x4* pb2 = (const i32x4*)(B + cb + 32 * D);
    const i32x4* pb3 = (const i32x4*)(B + cb + 48 * D);

    i32x4 Pa0, Pa1, Pa2, Pa3, Pb0, Pb1, Pb2, Pb3;
    i32x4 Qa0, Qa1, Qa2, Qa3, Qb0, Qb1, Qb2, Qb3;

#define LD(S, K)                                                     \
    S##a0 = pa0[K]; S##a1 = pa1[K]; S##a2 = pa2[K]; S##a3 = pa3[K]; \
    S##b0 = pb0[K]; S##b1 = pb1[K]; S##b2 = pb2[K]; S##b3 = pb3[K];
#define MF(a_, b_, r_, c_)                                           \
    acc[r_][c_] = __builtin_amdgcn_mfma_i32_16x16x64_i8(a_, b_, acc[r_][c_], 0, 0, 0)
#define MM(S)                                                        \
    MF(S##a0, S##b0, 0, 0); MF(S##a0, S##b1, 0, 1);                  \
    MF(S##a0, S##b2, 0, 2); MF(S##a0, S##b3, 0, 3);                  \
    MF(S##a1, S##b0, 1, 0); MF(S##a1, S##b1, 1, 1);                  \
    MF(S##a1, S##b2, 1, 2); MF(S##a1, S##b3, 1, 3);                  \
    MF(S##a2, S##b0, 2, 0); MF(S##a2, S##b1, 2, 1);                  \
    MF(S##a2, S##b2, 2, 2); MF(S##a2, S##b3, 2, 3);                  \
    MF(S##a3, S##b0, 3, 0); MF(S##a3, S##b1, 3, 1);                  \
    MF(S##a3, S##b2, 3, 2); MF(S##a3, S##b3, 3, 3);

    // Software pipeline, depth 1 K-step: issue step s+1's 8 loads, MFMA
    // step s. 16 steps fully unrolled (koff = s*4 element = s*64 bytes).
    LD(P, 0);
#pragma unroll
    for (int kb = 0; kb < 8; ++kb) {
        LD(Q, kb * 8 + 4);              // step 2kb+1
        MM(P);                          // step 2kb
        if (kb < 7) { LD(P, kb * 8 + 8); }  // step 2kb+2
        MM(Q);                          // step 2kb+1
    }
#undef LD
#undef MF
#undef MM

    // Epilogue: C map col = lane&15, row = quad*4 + reg.
#pragma unroll
    for (int rt = 0; rt < 4; ++rt) {
        float rsum[4] = {0.f, 0.f, 0.f, 0.f};
#pragma unroll
        for (int ct = 0; ct < 4; ++ct) {
#pragma unroll
            for (int reg = 0; reg < 4; ++reg) {
                const int grow = rowBase + wr * 64 + rt * 16 + quad * 4 + reg;
                const int gcol = colBase + wc * 64 + ct * 16 + colid;
                float logit = (float)acc[rt][ct][reg] * LSCALE;
                if (gcol == grow + N) logit += 1.0f;      // hard-negative weight
                if (gcol == grow) posdiag[grow] = logit;  // unique writer
                rsum[reg] += __expf(logit - CBIAS);
            }
        }
#pragma unroll
        for (int reg = 0; reg < 4; ++reg) {
            float v = rsum[reg];
            v += __shfl_xor(v, 1);
            v += __shfl_xor(v, 2);
            v += __shfl_xor(v, 4);
            v += __shfl_xor(v, 8);
            if (colid == 0) {
                const int grow = rowBase + wr * 64 + rt * 16 + quad * 4 + reg;
                atomicAdd(&rowsum[grow], v);
            }
        }
    }
}

// 16 blocks x 256 thr, one row per thread; wave-reduce then one atomic per
// wave into out (out zeroed by normalize earlier in the stream).
__global__ __launch_bounds__(256) void finalize_kernel(
    const float* __restrict__ rowsum, const float* __restrict__ posdiag,
    float* __restrict__ out) {
    const int i = blockIdx.x * 256 + threadIdx.x;
    float s = CBIAS + logf(rowsum[i]) - posdiag[i];
#pragma unroll
    for (int m = 32; m; m >>= 1) s += __shfl_down(s, m);
    if ((threadIdx.x & 63) == 0) atomicAdd(out, s * (1.0f / (float)N));
}

extern "C" void kernel_launch(void* const* d_in, const int* in_sizes, int n_in,
                              void* d_out, int out_size, void* d_ws, size_t ws_size,
                              hipStream_t stream) {
    const float* in0 = (const float*)d_in[0];  // input   [N, D] fp32
    const float* in1 = (const float*)d_in[1];  // target  [N, D] fp32
    const float* in2 = (const float*)d_in[2];  // hardneg [N, D] fp32

    // Workspace: Abuf N*D i8 (4 MiB) | Bbuf 2N*D i8 (8 MiB) | rowsum | posdiag
    unsigned char* Abuf = (unsigned char*)d_ws;
    unsigned char* Bbuf = Abuf + (size_t)N * D;
    float* rowsum = (float*)(Bbuf + (size_t)2 * N * D);
    float* posdiag = rowsum + N;

    normalize_kernel<<<3 * N / 4, 256, 0, stream>>>(in0, in1, in2, Abuf, Bbuf,
                                                    rowsum, (float*)d_out);
    gemm_lse_kernel<<<dim3(2 * N / 128, N / 128), 256, 0, stream>>>(
        Abuf, Bbuf, rowsum, posdiag);
    finalize_kernel<<<16, 256, 0, stream>>>(rowsum, posdiag, (float*)d_out);
}

// Round 9
// 148.243 us; speedup vs baseline: 1.5263x; 1.5263x over previous
//
#include <hip/hip_runtime.h>
#include <hip/hip_bf16.h>

// ContrastiveLoss: loss = mean_i [ logsumexp_j(logits[i,:]) - pos_sim[i,i] ]
// logits = [20*xn@tn^T | 20*xn@hn^T + I], rows normalized.
// Round 17: R15 champion (128.4us; gemm 45.6, 4 blocks/CU TLP, 2D XCD
// partition FETCH 16.5MB, 0-conflict swizzle) with ONE delta: the i8 MFMA
// shape 16x16x64 -> 32x32x32 (v_mfma_i32_32x32x32_i8, 4404 vs 3944 TOPS
// ubench): -12% MFMA-pipe cycles and HALF the MFMA instruction count
// (16/K-tile vs 32) at identical LDS traffic, identical 64-AGPR acc,
// identical staging/barriers -> the 4-blocks/CU residency is preserved.
//  - R16 lesson (gemm 145us, MfmaUtil 9%): direct-from-global frag loads
//    are a 16-line gather per instruction, latency-bound; LDS staging is
//    mandatory. BANNED.
//  - R9-R12: intra-block schedules NULL at low residency; TLP is the lever
//    (R13: 77->44.4 matched prediction). R14: device fences in hot path
//    BANNED. scaled-MFMA banned (R2/R4); b64 LDS reads banned (R5);
//    setprio off (m190: negative on multi-block GEMM).
//  - 32x32 frag: row = lane&31, k-bytes (lane>>5)*16+j -> logical chunk
//    2s+(lane>>5), phys = logical ^ (lane&7) (same proven XOR family).
//  - C/D: col = lane&31, row = (reg&3)+8*(reg>>2)+4*(lane>>5) (m74/m101,
//    dtype-independent). Epilogue merges ac=0/1 before the 32-lane reduce
//    -> still 64 atomics/wave.
//  - logit = acc * (20/127^2); diag cancellation keeps i8 loss error ~1e-3.

#define AS1 __attribute__((address_space(1)))
#define AS3 __attribute__((address_space(3)))

constexpr int N = 4096;
constexpr int D = 1024;            // elements per row == bytes per i8 row
constexpr float QSCALE = 127.0f;
constexpr float LSCALE = 20.0f / (127.0f * 127.0f);  // acc -> logit
constexpr float CBIAS = 21.0f;     // >= max possible logit (20*1 + 1)

typedef int i32x4 __attribute__((ext_vector_type(4)));
typedef int i32x16 __attribute__((ext_vector_type(16)));

// 3072 blocks x 256. One row per wave, 4 coalesced passes: pass j, lane L
// loads float4 #(L+64j) (1KB/inst contiguous) and stores the 4 quantized
// bytes as u32 #(L+64j) (256B/inst contiguous).
// Blocks 0..15 zero rowsum; block 0 zeroes out[0] for finalize's atomics.
__global__ __launch_bounds__(256) void normalize_kernel(
    const float* __restrict__ in0, const float* __restrict__ in1,
    const float* __restrict__ in2, unsigned char* __restrict__ Abuf,
    unsigned char* __restrict__ Bbuf, float* __restrict__ rowsum,
    float* __restrict__ outp) {
    const int t = threadIdx.x, lane = t & 63, wave = t >> 6;
    if (blockIdx.x < 16) rowsum[blockIdx.x * 256 + t] = 0.f;
    if (blockIdx.x == 0 && t == 0) outp[0] = 0.f;
    const int row = blockIdx.x * 4 + wave;  // 0..12287
    const int mat = row >> 12, r = row & (N - 1);
    const float* src = (mat == 0) ? in0 : (mat == 1) ? in1 : in2;
    unsigned char* dst = (mat == 0) ? (Abuf + (size_t)r * D)
                       : (mat == 1) ? (Bbuf + (size_t)r * D)
                                    : (Bbuf + (size_t)(r + N) * D);
    const float4* s4 = (const float4*)(src + (size_t)r * D);
    float4 v[4];
    float p = 0.f;
#pragma unroll
    for (int j = 0; j < 4; ++j) {
        v[j] = s4[lane + 64 * j];  // coalesced: 64 consecutive float4/inst
        p += v[j].x * v[j].x + v[j].y * v[j].y + v[j].z * v[j].z + v[j].w * v[j].w;
    }
#pragma unroll
    for (int m = 1; m < 64; m <<= 1) p += __shfl_xor(p, m);
    const float s = QSCALE / fmaxf(sqrtf(p), 1e-8f);
    unsigned int* d32 = (unsigned int*)dst;
#pragma unroll
    for (int j = 0; j < 4; ++j) {
        int q0 = min(127, max(-127, __float2int_rn(v[j].x * s)));
        int q1 = min(127, max(-127, __float2int_rn(v[j].y * s)));
        int q2 = min(127, max(-127, __float2int_rn(v[j].z * s)));
        int q3 = min(127, max(-127, __float2int_rn(v[j].w * s)));
        d32[lane + 64 * j] = (q0 & 255) | ((q1 & 255) << 8) | ((q2 & 255) << 16)
                           | ((unsigned)(q3 & 255) << 24);
    }
}

// 128x128 tile, BK=128 i8-bytes, 4 waves 2x2, wave 64x64 via 2x2 of
// 32x32x32 i8 MFMA x 4 K-steps (s) per staged tile, b128 frag reads.
// A:[N,D] i8, B:[2N,D] i8, row-major.
// Frag: row = lane&31, k-bytes (lane>>5)*16 + j within K-step s's 32B.
// C/D: col = lane&31, row = (reg&3) + 8*(reg>>2) + 4*(lane>>5).
// __launch_bounds__(256,4): 4 blocks/CU for inter-block MFMA/stage overlap
// (R13's proven lever).
__global__ __launch_bounds__(256, 4) void gemm_lse_kernel(
    const unsigned char* __restrict__ A, const unsigned char* __restrict__ B,
    float* __restrict__ rowsum, float* __restrict__ posdiag) {
    __shared__ __align__(16) char As[128 * 128];  // 16 KiB
    __shared__ __align__(16) char Bs[128 * 128];  // 16 KiB

    const int tid = threadIdx.x;
    const int lane = tid & 63;
    const int wave = tid >> 6;
    const int wr = wave >> 1, wc = wave & 1;
    const int l31 = lane & 31, hi = lane >> 5, l7 = lane & 7;

    // 2D XCD partition (R14/R15-proven: FETCH 39->16.5MB): XCD x owns the
    // 16x16-tile region rows [16*(x>>2),+16) x cols [16*(x&3),+16).
    const int flat = blockIdx.y * 64 + blockIdx.x;
    const int xcd = flat & 7, tt = flat >> 3;  // tt = 0..255 within XCD
    const int rowBase = (((xcd >> 2) << 4) + (tt & 15)) * 128;
    const int colBase = (((xcd & 3) << 4) + (tt >> 4)) * 128;

    i32x16 acc[2][2];
#pragma unroll
    for (int i = 0; i < 2; ++i)
#pragma unroll
        for (int j = 0; j < 2; ++j)
#pragma unroll
            for (int e = 0; e < 16; ++e) acc[i][j][e] = 0;

    // Staging (R8-proven, 0 conflicts): thread t fills 16B phys-chunks
    // t+256j; phys chunk c -> row c>>3, phys col c&7; logical col =
    // (c&7)^(row&7); row&7 == (t>>3)&7 for all j.
    const int srow = tid >> 3;                      // 0..31
    const int scol = (tid & 7) ^ ((tid >> 3) & 7);  // 16B units
    const unsigned char* gAb = A + (size_t)(rowBase + srow) * D + scol * 16;
    const unsigned char* gBb = B + (size_t)(colBase + srow) * D + scol * 16;

    // Frag offsets: row R = (wr|wc)*64 + ar*32 + l31 -> R&7 == l7 (ar*32 is
    // 0 mod 8). K-step s: logical chunk 2s+hi, phys = (2s+hi)^l7.
    // ar/ac stride 32*128 = 4096 folded into the read offset immediate.
    const int arow0 = (wr * 64 + l31) * 128;
    const int brow0 = (wc * 64 + l31) * 128;
    int chk[4];
#pragma unroll
    for (int s = 0; s < 4; ++s) chk[s] = ((2 * s + hi) ^ l7) * 16;

    for (int kb = 0; kb < D / 128; ++kb) {
        const int k0 = kb * 128;
        __syncthreads();  // prior reads done before overwrite
        const unsigned char* gA = gAb + k0;  // rows srow+32j at +32768j
        const unsigned char* gB = gBb + k0;
#pragma unroll
        for (int j = 0; j < 4; ++j) {
            __builtin_amdgcn_global_load_lds((const AS1 void*)(gA + 32768 * j),
                (AS3 void*)(As + (tid + 256 * j) * 16), 16, 0, 0);
            __builtin_amdgcn_global_load_lds((const AS1 void*)(gB + 32768 * j),
                (AS3 void*)(Bs + (tid + 256 * j) * 16), 16, 0, 0);
        }
        __syncthreads();  // staged data visible

#pragma unroll
        for (int s = 0; s < 4; ++s) {
            i32x4 a0 = *(const i32x4*)(As + arow0 + chk[s]);
            i32x4 a1 = *(const i32x4*)(As + arow0 + 4096 + chk[s]);
            i32x4 b0 = *(const i32x4*)(Bs + brow0 + chk[s]);
            i32x4 b1 = *(const i32x4*)(Bs + brow0 + 4096 + chk[s]);
            acc[0][0] = __builtin_amdgcn_mfma_i32_32x32x32_i8(a0, b0, acc[0][0], 0, 0, 0);
            acc[0][1] = __builtin_amdgcn_mfma_i32_32x32x32_i8(a0, b1, acc[0][1], 0, 0, 0);
            acc[1][0] = __builtin_amdgcn_mfma_i32_32x32x32_i8(a1, b0, acc[1][0], 0, 0, 0);
            acc[1][1] = __builtin_amdgcn_mfma_i32_32x32x32_i8(a1, b1, acc[1][1], 0, 0, 0);
        }
    }

    // Epilogue: C map col = lane&31, row = (reg&3)+8*(reg>>2)+4*hi.
    // Merge ac=0/1 partials in-register, reduce across the 32-lane half
    // (xor 1..16 stays within each half), one atomic per row per wave.
#pragma unroll
    for (int ar = 0; ar < 2; ++ar) {
#pragma unroll
        for (int reg = 0; reg < 16; ++reg) {
            const int crow = (reg & 3) + 8 * (reg >> 2) + 4 * hi;
            const int grow = rowBase + wr * 64 + ar * 32 + crow;
            float rs = 0.f;
#pragma unroll
            for (int ac = 0; ac < 2; ++ac) {
                const int gcol = colBase + wc * 64 + ac * 32 + l31;
                float logit = (float)acc[ar][ac][reg] * LSCALE;
                if (gcol == grow + N) logit += 1.0f;      // hard-negative weight
                if (gcol == grow) posdiag[grow] = logit;  // unique writer
                rs += __expf(logit - CBIAS);
            }
            rs += __shfl_xor(rs, 1);
            rs += __shfl_xor(rs, 2);
            rs += __shfl_xor(rs, 4);
            rs += __shfl_xor(rs, 8);
            rs += __shfl_xor(rs, 16);
            if (l31 == 0) atomicAdd(&rowsum[grow], rs);
        }
    }
}

// 16 blocks x 256 thr, one row per thread; wave-reduce then one atomic per
// wave into out (out zeroed by normalize earlier in the stream).
__global__ __launch_bounds__(256) void finalize_kernel(
    const float* __restrict__ rowsum, const float* __restrict__ posdiag,
    float* __restrict__ out) {
    const int i = blockIdx.x * 256 + threadIdx.x;
    float s = CBIAS + logf(rowsum[i]) - posdiag[i];
#pragma unroll
    for (int m = 32; m; m >>= 1) s += __shfl_down(s, m);
    if ((threadIdx.x & 63) == 0) atomicAdd(out, s * (1.0f / (float)N));
}

extern "C" void kernel_launch(void* const* d_in, const int* in_sizes, int n_in,
                              void* d_out, int out_size, void* d_ws, size_t ws_size,
                              hipStream_t stream) {
    const float* in0 = (const float*)d_in[0];  // input   [N, D] fp32
    const float* in1 = (const float*)d_in[1];  // target  [N, D] fp32
    const float* in2 = (const float*)d_in[2];  // hardneg [N, D] fp32

    // Workspace: Abuf N*D i8 (4 MiB) | Bbuf 2N*D i8 (8 MiB) | rowsum | posdiag
    unsigned char* Abuf = (unsigned char*)d_ws;
    unsigned char* Bbuf = Abuf + (size_t)N * D;
    float* rowsum = (float*)(Bbuf + (size_t)2 * N * D);
    float* posdiag = rowsum + N;

    normalize_kernel<<<3 * N / 4, 256, 0, stream>>>(in0, in1, in2, Abuf, Bbuf,
                                                    rowsum, (float*)d_out);
    gemm_lse_kernel<<<dim3(2 * N / 128, N / 128), 256, 0, stream>>>(
        Abuf, Bbuf, rowsum, posdiag);
    finalize_kernel<<<16, 256, 0, stream>>>(rowsum, posdiag, (float*)d_out);
}

// Round 10
// 128.822 us; speedup vs baseline: 1.7564x; 1.1508x over previous
//
#include <hip/hip_runtime.h>
#include <hip/hip_bf16.h>

// ContrastiveLoss: loss = mean_i [ logsumexp_j(logits[i,:]) - pos_sim[i,i] ]
// logits = [20*xn@tn^T | 20*xn@hn^T + I], rows normalized.
// Round 18: counted-vmcnt prefetch WITH TLP (the untested combination).
//  - R17 (32x32x32 MFMA) REVERTED: 4.19M bank-conflict cycles, gemm 66.8us.
//    16x16x64 + its proven swizzle family is the only conflict-free layout.
//  - R10's deep pipeline failed at 1 block/CU; R13 proved residency is the
//    mechanism. This round: BK=64 -> slot 16KB, 3 slots = 48KB -> 3
//    blocks/CU (regs still 4 waves/SIMD), prefetch 2 tiles ahead,
//    vmcnt(4) counted (never 0 mid-loop), ONE barrier/tile (16 total ==
//    R15's barrier count), stage issued AFTER the barrier so slot reuse
//    (distance 3) is barrier-ordered -- race-free by construction.
//  - Same per-block totals as R15: 128 b128 reads, 256 MFMA, 64 gloads.
//  - 64B-row swizzle: frag chunk = quad; phys = quad ^ ((colid>>1)&3);
//    banks = 16*(row&1) + 4*phys -> all 32 distinct per 8-lane phase
//    (enumerated). Staging linear; inverse XOR folded into global col:
//    gcol16 = (t&3) ^ ((t>>3)&3).
//  - Ledger: no-LDS banned (R16); 32x32 banned (R17); device fences banned
//    (R14); scaled-MFMA banned (R2/R4); b64 reads banned (R5); setprio off
//    (m190). 2D XCD partition proven (R14/R15: FETCH 39->16.5MB).
//  - logit = acc * (20/127^2); diag cancellation keeps i8 loss error ~1e-3.

#define AS1 __attribute__((address_space(1)))
#define AS3 __attribute__((address_space(3)))

constexpr int N = 4096;
constexpr int D = 1024;            // elements per row == bytes per i8 row
constexpr float QSCALE = 127.0f;
constexpr float LSCALE = 20.0f / (127.0f * 127.0f);  // acc -> logit
constexpr float CBIAS = 21.0f;     // >= max possible logit (20*1 + 1)

typedef int i32x4 __attribute__((ext_vector_type(4)));

// 3072 blocks x 256. One row per wave, 4 coalesced passes: pass j, lane L
// loads float4 #(L+64j) (1KB/inst contiguous) and stores the 4 quantized
// bytes as u32 #(L+64j) (256B/inst contiguous).
// Blocks 0..15 zero rowsum; block 0 zeroes out[0] for finalize's atomics.
__global__ __launch_bounds__(256) void normalize_kernel(
    const float* __restrict__ in0, const float* __restrict__ in1,
    const float* __restrict__ in2, unsigned char* __restrict__ Abuf,
    unsigned char* __restrict__ Bbuf, float* __restrict__ rowsum,
    float* __restrict__ outp) {
    const int t = threadIdx.x, lane = t & 63, wave = t >> 6;
    if (blockIdx.x < 16) rowsum[blockIdx.x * 256 + t] = 0.f;
    if (blockIdx.x == 0 && t == 0) outp[0] = 0.f;
    const int row = blockIdx.x * 4 + wave;  // 0..12287
    const int mat = row >> 12, r = row & (N - 1);
    const float* src = (mat == 0) ? in0 : (mat == 1) ? in1 : in2;
    unsigned char* dst = (mat == 0) ? (Abuf + (size_t)r * D)
                       : (mat == 1) ? (Bbuf + (size_t)r * D)
                                    : (Bbuf + (size_t)(r + N) * D);
    const float4* s4 = (const float4*)(src + (size_t)r * D);
    float4 v[4];
    float p = 0.f;
#pragma unroll
    for (int j = 0; j < 4; ++j) {
        v[j] = s4[lane + 64 * j];  // coalesced: 64 consecutive float4/inst
        p += v[j].x * v[j].x + v[j].y * v[j].y + v[j].z * v[j].z + v[j].w * v[j].w;
    }
#pragma unroll
    for (int m = 1; m < 64; m <<= 1) p += __shfl_xor(p, m);
    const float s = QSCALE / fmaxf(sqrtf(p), 1e-8f);
    unsigned int* d32 = (unsigned int*)dst;
#pragma unroll
    for (int j = 0; j < 4; ++j) {
        int q0 = min(127, max(-127, __float2int_rn(v[j].x * s)));
        int q1 = min(127, max(-127, __float2int_rn(v[j].y * s)));
        int q2 = min(127, max(-127, __float2int_rn(v[j].z * s)));
        int q3 = min(127, max(-127, __float2int_rn(v[j].w * s)));
        d32[lane + 64 * j] = (q0 & 255) | ((q1 & 255) << 8) | ((q2 & 255) << 16)
                           | ((unsigned)(q3 & 255) << 24);
    }
}

// 128x128 tile, BK=64 i8-bytes, 16 K-tiles, 4 waves 2x2, wave 64x64 via
// 4x4 of 16x16x64 i8 MFMA per K-tile, b128 frag reads.
// A:[N,D] i8, B:[2N,D] i8, row-major (frag = 16 contig bytes,
// row = lane&15, k = (lane>>4)*16 + j).
// C/D: col = lane&15, row = (lane>>4)*4 + reg (m89-verified).
// 3-slot LDS rotation (slot = A 8KB | B 8KB), prefetch depth 2,
// vmcnt(4) counted, one raw barrier per K-tile, stage after barrier.
__global__ __launch_bounds__(256, 4) void gemm_lse_kernel(
    const unsigned char* __restrict__ A, const unsigned char* __restrict__ B,
    float* __restrict__ rowsum, float* __restrict__ posdiag) {
    __shared__ __align__(16) char smem[3 * 16384];  // 48 KiB -> 3 blocks/CU

    const int tid = threadIdx.x;
    const int lane = tid & 63;
    const int wave = tid >> 6;
    const int wr = wave >> 1, wc = wave & 1;
    const int quad = lane >> 4, colid = lane & 15;

    // 2D XCD partition (R14/R15-proven: FETCH 39->16.5MB): XCD x owns the
    // 16x16-tile region rows [16*(x>>2),+16) x cols [16*(x&3),+16).
    const int flat = blockIdx.y * 64 + blockIdx.x;
    const int xcd = flat & 7, tt = flat >> 3;  // tt = 0..255 within XCD
    const int rowBase = (((xcd >> 2) << 4) + (tt & 15)) * 128;
    const int colBase = (((xcd & 3) << 4) + (tt >> 4)) * 128;

    i32x4 acc[4][4];
#pragma unroll
    for (int i = 0; i < 4; ++i)
#pragma unroll
        for (int j = 0; j < 4; ++j) acc[i][j] = {0, 0, 0, 0};

    // Staging: per K-tile, panel = 128 rows x 64B = 512 16B-chunks/matrix.
    // Thread t writes chunks t (rows 0..63) and t+256 (rows 64..127) at
    // linear LDS byte (t+256j)*16. Phys chunk c: row = c>>2, phys col c&3;
    // logical col = (c&3) ^ ((row>>1)&3) = (t&3) ^ ((t>>3)&3) (j-invariant:
    // +64 rows -> +32 on row>>1 -> &3 unchanged).
    const int st_row = tid >> 2;                      // 0..63
    const int st_c = (tid & 3) ^ ((tid >> 3) & 3);    // 16B units in 64B
    const unsigned char* pA0 = A + (size_t)(rowBase + st_row) * D + st_c * 16;
    const unsigned char* pA1 = A + (size_t)(rowBase + st_row + 64) * D + st_c * 16;
    const unsigned char* pB0 = B + (size_t)(colBase + st_row) * D + st_c * 16;
    const unsigned char* pB1 = B + (size_t)(colBase + st_row + 64) * D + st_c * 16;

    // Frag read: row R = (wr|wc)*64 + rt*16 + colid; (R>>1)&3 = (colid>>1)&3
    // (rt*16, wr*64 are 0 mod 8 on R>>1's low bits). Logical chunk = quad;
    // phys = quad ^ ((colid>>1)&3). rt stride 16*64 = 1024 (imm).
    const int cph = (quad ^ ((colid >> 1) & 3)) * 16;
    const int abase = (wr * 64 + colid) * 64 + cph;         // in slot A half
    const int bbase = 8192 + (wc * 64 + colid) * 64 + cph;  // in slot B half

#define STAGE(KT, SL)                                                        \
    {                                                                        \
        char* dst_ = smem + (SL) * 16384;                                    \
        __builtin_amdgcn_global_load_lds((const AS1 void*)(pA0 + (KT) * 64), \
            (AS3 void*)(dst_ + tid * 16), 16, 0, 0);                         \
        __builtin_amdgcn_global_load_lds((const AS1 void*)(pA1 + (KT) * 64), \
            (AS3 void*)(dst_ + (tid + 256) * 16), 16, 0, 0);                 \
        __builtin_amdgcn_global_load_lds((const AS1 void*)(pB0 + (KT) * 64), \
            (AS3 void*)(dst_ + 8192 + tid * 16), 16, 0, 0);                  \
        __builtin_amdgcn_global_load_lds((const AS1 void*)(pB1 + (KT) * 64), \
            (AS3 void*)(dst_ + 8192 + (tid + 256) * 16), 16, 0, 0);          \
    }

#define COMPUTE(SL)                                                          \
    {                                                                        \
        const char* s_ = smem + (SL) * 16384;                                \
        i32x4 a[4], b[4];                                                    \
        _Pragma("unroll") for (int rt = 0; rt < 4; ++rt)                     \
            a[rt] = *(const i32x4*)(s_ + abase + rt * 1024);                 \
        _Pragma("unroll") for (int ct = 0; ct < 4; ++ct)                     \
            b[ct] = *(const i32x4*)(s_ + bbase + ct * 1024);                 \
        _Pragma("unroll") for (int rt = 0; rt < 4; ++rt)                     \
            _Pragma("unroll") for (int ct = 0; ct < 4; ++ct)                 \
                acc[rt][ct] = __builtin_amdgcn_mfma_i32_16x16x64_i8(         \
                    a[rt], b[ct], acc[rt][ct], 0, 0, 0);                     \
    }

    // Prologue: prefetch tiles 0 and 1.
    STAGE(0, 0)
    STAGE(1, 1)

    // Iter k: vmcnt(4) [only stage(k+1)'s 4 loads may remain -> tile k
    // resident] -> barrier [orders epoch k-1's reads before the coming
    // overwrite of slot (k+2)%3 = (k-1)%3] -> stage(k+2) -> read+MFMA(k).
#pragma unroll
    for (int k = 0; k < 16; ++k) {
        if (k < 15)
            asm volatile("s_waitcnt vmcnt(4)" ::: "memory");
        else
            asm volatile("s_waitcnt vmcnt(0)" ::: "memory");
        __builtin_amdgcn_s_barrier();
        if (k < 14) {
            switch ((k + 2) % 3) {
                case 0: STAGE(k + 2, 0) break;
                case 1: STAGE(k + 2, 1) break;
                default: STAGE(k + 2, 2) break;
            }
        }
        COMPUTE(k % 3)
    }
#undef STAGE
#undef COMPUTE

    // Epilogue: C map col = lane&15, row = quad*4 + reg (R15 verbatim).
#pragma unroll
    for (int rt = 0; rt < 4; ++rt) {
        float rsum[4] = {0.f, 0.f, 0.f, 0.f};
#pragma unroll
        for (int ct = 0; ct < 4; ++ct) {
#pragma unroll
            for (int reg = 0; reg < 4; ++reg) {
                const int grow = rowBase + wr * 64 + rt * 16 + quad * 4 + reg;
                const int gcol = colBase + wc * 64 + ct * 16 + colid;
                float logit = (float)acc[rt][ct][reg] * LSCALE;
                if (gcol == grow + N) logit += 1.0f;      // hard-negative weight
                if (gcol == grow) posdiag[grow] = logit;  // unique writer
                rsum[reg] += __expf(logit - CBIAS);
            }
        }
#pragma unroll
        for (int reg = 0; reg < 4; ++reg) {
            float v = rsum[reg];
            v += __shfl_xor(v, 1);
            v += __shfl_xor(v, 2);
            v += __shfl_xor(v, 4);
            v += __shfl_xor(v, 8);
            if (colid == 0) {
                const int grow = rowBase + wr * 64 + rt * 16 + quad * 4 + reg;
                atomicAdd(&rowsum[grow], v);
            }
        }
    }
}

// 16 blocks x 256 thr, one row per thread; wave-reduce then one atomic per
// wave into out (out zeroed by normalize earlier in the stream).
__global__ __launch_bounds__(256) void finalize_kernel(
    const float* __restrict__ rowsum, const float* __restrict__ posdiag,
    float* __restrict__ out) {
    const int i = blockIdx.x * 256 + threadIdx.x;
    float s = CBIAS + logf(rowsum[i]) - posdiag[i];
#pragma unroll
    for (int m = 32; m; m >>= 1) s += __shfl_down(s, m);
    if ((threadIdx.x & 63) == 0) atomicAdd(out, s * (1.0f / (float)N));
}

extern "C" void kernel_launch(void* const* d_in, const int* in_sizes, int n_in,
                              void* d_out, int out_size, void* d_ws, size_t ws_size,
                              hipStream_t stream) {
    const float* in0 = (const float*)d_in[0];  // input   [N, D] fp32
    const float* in1 = (const float*)d_in[1];  // target  [N, D] fp32
    const float* in2 = (const float*)d_in[2];  // hardneg [N, D] fp32

    // Workspace: Abuf N*D i8 (4 MiB) | Bbuf 2N*D i8 (8 MiB) | rowsum | posdiag
    unsigned char* Abuf = (unsigned char*)d_ws;
    unsigned char* Bbuf = Abuf + (size_t)N * D;
    float* rowsum = (float*)(Bbuf + (size_t)2 * N * D);
    float* posdiag = rowsum + N;

    normalize_kernel<<<3 * N / 4, 256, 0, stream>>>(in0, in1, in2, Abuf, Bbuf,
                                                    rowsum, (float*)d_out);
    gemm_lse_kernel<<<dim3(2 * N / 128, N / 128), 256, 0, stream>>>(
        Abuf, Bbuf, rowsum, posdiag);
    finalize_kernel<<<16, 256, 0, stream>>>(rowsum, posdiag, (float*)d_out);
}